// Round 1
// baseline (818.950 us; speedup 1.0000x reference)
//
#include <hip/hip_runtime.h>
#include <stdint.h>
#include <stddef.h>

#define FIN 512
#define FOUT 128

typedef __attribute__((ext_vector_type(8))) short short8;
typedef __attribute__((ext_vector_type(4))) float f32x4;

__device__ __forceinline__ unsigned short f2bf(float f) {
  unsigned u = __builtin_bit_cast(unsigned, f);
  u = (u + 0x7fffu + ((u >> 16) & 1u)) >> 16;
  return (unsigned short)u;
}
__device__ __forceinline__ float bf2f(unsigned short h) {
  unsigned u = ((unsigned)h) << 16;
  return __builtin_bit_cast(float, u);
}

// theta [512][128] f32 -> thetaT [128][512] bf16
__global__ void prep_theta_k(const float* __restrict__ theta,
                             unsigned short* __restrict__ thetaT) {
  int idx = blockIdx.x * blockDim.x + threadIdx.x;  // 65536 = 128*512
  int n = idx >> 9;
  int k = idx & 511;
  thetaT[idx] = f2bf(theta[k * FOUT + n]);
}

// y[M][128] bf16 = x[M][512] f32 @ thetaT^T, via 16x16x32 bf16 MFMA.
// 128x128 tile, BK=32, 4 waves (2x2, each 64x64).
__global__ __launch_bounds__(256) void gemm_k(const float* __restrict__ x,
                                              const unsigned short* __restrict__ thetaT,
                                              unsigned short* __restrict__ yb, int M) {
  // padded leading dim 40 (80B rows): fragment ds_read_b128 lands 2-way (free)
  __shared__ __align__(16) unsigned short lA[128 * 40];
  __shared__ __align__(16) unsigned short lB[128 * 40];
  const int tid = threadIdx.x;
  const int row0 = blockIdx.x * 128;
  const int wave = tid >> 6, lane = tid & 63;
  const int wm = wave >> 1, wn = wave & 1;
  const int fr = lane & 15, fq = lane >> 4;
  const int arow = tid >> 1, ahalf = tid & 1;

  f32x4 acc[4][4] = {};

  const int grow = row0 + arow;
  const bool aval = (grow < M);
  const float* asrc = x + (size_t)(aval ? grow : 0) * FIN + ahalf * 16;
  const unsigned short* bsrc = thetaT + (size_t)arow * FIN + ahalf * 16;

  for (int k0 = 0; k0 < FIN; k0 += 32) {
    // ---- stage A (f32 -> bf16) ----
    float av[16];
    if (aval) {
      const float4* p = (const float4*)(asrc + k0);
      float4 v0 = p[0], v1 = p[1], v2 = p[2], v3 = p[3];
      av[0] = v0.x; av[1] = v0.y; av[2] = v0.z; av[3] = v0.w;
      av[4] = v1.x; av[5] = v1.y; av[6] = v1.z; av[7] = v1.w;
      av[8] = v2.x; av[9] = v2.y; av[10] = v2.z; av[11] = v2.w;
      av[12] = v3.x; av[13] = v3.y; av[14] = v3.z; av[15] = v3.w;
    } else {
      for (int i = 0; i < 16; i++) av[i] = 0.f;
    }
    unsigned ap[8];
    for (int i = 0; i < 8; i++)
      ap[i] = (unsigned)f2bf(av[2 * i]) | ((unsigned)f2bf(av[2 * i + 1]) << 16);
    uint4* aw = (uint4*)&lA[arow * 40 + ahalf * 16];
    aw[0] = make_uint4(ap[0], ap[1], ap[2], ap[3]);
    aw[1] = make_uint4(ap[4], ap[5], ap[6], ap[7]);

    // ---- stage B (already bf16, straight copy) ----
    const uint4* bp = (const uint4*)(bsrc + k0);
    uint4 b0 = bp[0], b1 = bp[1];
    uint4* bw = (uint4*)&lB[arow * 40 + ahalf * 16];
    bw[0] = b0; bw[1] = b1;

    __syncthreads();

    short8 af[4], bfv[4];
#pragma unroll
    for (int m = 0; m < 4; m++)
      af[m] = *(const short8*)&lA[(wm * 64 + m * 16 + fr) * 40 + fq * 8];
#pragma unroll
    for (int n = 0; n < 4; n++)
      bfv[n] = *(const short8*)&lB[(wn * 64 + n * 16 + fr) * 40 + fq * 8];
#pragma unroll
    for (int m = 0; m < 4; m++)
#pragma unroll
      for (int n = 0; n < 4; n++)
        acc[m][n] = __builtin_amdgcn_mfma_f32_16x16x32_bf16(af[m], bfv[n], acc[m][n], 0, 0, 0);

    __syncthreads();
  }

  // C/D layout: col = lane&15, row = (lane>>4)*4 + reg
#pragma unroll
  for (int m = 0; m < 4; m++) {
    int rbase = row0 + wm * 64 + m * 16 + fq * 4;
#pragma unroll
    for (int j = 0; j < 4; j++) {
      int r = rbase + j;
      if (r < M) {
        unsigned short* dst = yb + (size_t)r * FOUT + wn * 64;
#pragma unroll
        for (int n = 0; n < 4; n++) dst[n * 16 + fr] = f2bf(acc[m][n][j]);
      }
    }
  }
}

__global__ void hist_k(const int* __restrict__ rows, int* __restrict__ counts, int E) {
  int i = blockIdx.x * blockDim.x + threadIdx.x;
  int stride = gridDim.x * blockDim.x;
  for (; i < E; i += stride) atomicAdd(&counts[rows[i]], 1);
}

// single-block exclusive scan over counts[N] -> offsets[N+1], cursor = copy
__global__ __launch_bounds__(1024) void scan_k(const int* __restrict__ counts,
                                               int* __restrict__ offsets,
                                               int* __restrict__ cursor, int N) {
  __shared__ int part[1024];
  int t = threadIdx.x;
  int chunk = (N + 1023) / 1024;
  int lo = t * chunk;
  int hi = lo + chunk; if (hi > N) hi = N;
  int s = 0;
  for (int i = lo; i < hi; i++) s += counts[i];
  part[t] = s;
  __syncthreads();
  for (int off = 1; off < 1024; off <<= 1) {
    int v = (t >= off) ? part[t - off] : 0;
    __syncthreads();
    part[t] += v;
    __syncthreads();
  }
  int run = (t == 0) ? 0 : part[t - 1];
  for (int i = lo; i < hi; i++) {
    offsets[i] = run;
    cursor[i] = run;
    run += counts[i];
  }
  if (t == 0) offsets[N] = part[1023];
}

__global__ void scatter_k(const int* __restrict__ rows, const int* __restrict__ cols,
                          const float* __restrict__ vals, int* __restrict__ cursor,
                          int* __restrict__ sc, float* __restrict__ sv, int E) {
  int i = blockIdx.x * blockDim.x + threadIdx.x;
  int stride = gridDim.x * blockDim.x;
  for (; i < E; i += stride) {
    int r = rows[i];
    int p = atomicAdd(&cursor[r], 1);
    sc[p] = cols[i];
    sv[p] = vals[i];
  }
}

// one 32-lane group per row: acc 4 feats/lane in regs, fused bias+relu store
__global__ __launch_bounds__(256) void row_k(const int* __restrict__ offsets,
                                             const int* __restrict__ sc,
                                             const float* __restrict__ sv,
                                             const unsigned short* __restrict__ yb,
                                             const float* __restrict__ bias,
                                             float* __restrict__ out, int N) {
  int gid = blockIdx.x * blockDim.x + threadIdx.x;
  int r = gid >> 5, sl = gid & 31;
  if (r >= N) return;
  int s = offsets[r], e = offsets[r + 1];
  float a0 = 0.f, a1 = 0.f, a2 = 0.f, a3 = 0.f;
  for (int i = s; i < e; i++) {
    int c = sc[i];
    float v = sv[i];
    uint2 raw = *(const uint2*)(yb + (size_t)c * FOUT + sl * 4);
    a0 += v * bf2f((unsigned short)(raw.x & 0xffffu));
    a1 += v * bf2f((unsigned short)(raw.x >> 16));
    a2 += v * bf2f((unsigned short)(raw.y & 0xffffu));
    a3 += v * bf2f((unsigned short)(raw.y >> 16));
  }
  const float4 bb = *(const float4*)(bias + sl * 4);
  float4 o;
  o.x = fmaxf(a0 + bb.x, 0.f);
  o.y = fmaxf(a1 + bb.y, 0.f);
  o.z = fmaxf(a2 + bb.z, 0.f);
  o.w = fmaxf(a3 + bb.w, 0.f);
  *(float4*)(out + (size_t)r * FOUT + sl * 4) = o;
}

extern "C" void kernel_launch(void* const* d_in, const int* in_sizes, int n_in,
                              void* d_out, int out_size, void* d_ws, size_t ws_size,
                              hipStream_t stream) {
  const float* x = (const float*)d_in[0];
  const int* rows = (const int*)d_in[1];
  const int* cols = (const int*)d_in[2];
  const float* vals = (const float*)d_in[3];
  const float* theta = (const float*)d_in[4];
  const float* bias = (const float*)d_in[5];
  float* out = (float*)d_out;
  const int M = in_sizes[0] / FIN;  // 100000
  const int E = in_sizes[1];        // 3200000

  char* w = (char*)d_ws;
  auto alloc = [&](size_t bytes) {
    char* p = w;
    w += (bytes + 255) & ~(size_t)255;
    return p;
  };
  unsigned short* yb = (unsigned short*)alloc((size_t)M * FOUT * 2);
  unsigned short* thetaT = (unsigned short*)alloc((size_t)FIN * FOUT * 2);
  int* counts = (int*)alloc((size_t)M * 4);
  int* offsets = (int*)alloc((size_t)(M + 1) * 4);
  int* cursor = (int*)alloc((size_t)M * 4);
  int* sc = (int*)alloc((size_t)E * 4);
  float* sv = (float*)alloc((size_t)E * 4);

  hipMemsetAsync(counts, 0, (size_t)M * 4, stream);
  prep_theta_k<<<(FIN * FOUT) / 256, 256, 0, stream>>>(theta, thetaT);
  gemm_k<<<(M + 127) / 128, 256, 0, stream>>>(x, thetaT, yb, M);
  hist_k<<<2048, 256, 0, stream>>>(rows, counts, E);
  scan_k<<<1, 1024, 0, stream>>>(counts, offsets, cursor, M);
  scatter_k<<<2048, 256, 0, stream>>>(rows, cols, vals, cursor, sc, sv, E);
  row_k<<<(M * 32 + 255) / 256, 256, 0, stream>>>(offsets, sc, sv, yb, bias, out, M);
}

// Round 2
// 610.866 us; speedup vs baseline: 1.3406x; 1.3406x over previous
//
#include <hip/hip_runtime.h>
#include <stdint.h>
#include <stddef.h>

#define FIN 512
#define FOUT 128

typedef __attribute__((ext_vector_type(8))) short short8;
typedef __attribute__((ext_vector_type(4))) float f32x4;

__device__ __forceinline__ unsigned short f2bf(float f) {
  unsigned u = __builtin_bit_cast(unsigned, f);
  u = (u + 0x7fffu + ((u >> 16) & 1u)) >> 16;
  return (unsigned short)u;
}
__device__ __forceinline__ float bf2f(unsigned short h) {
  unsigned u = ((unsigned)h) << 16;
  return __builtin_bit_cast(float, u);
}

// theta [512][128] f32 -> thetaT [128][512] bf16
__global__ void prep_theta_k(const float* __restrict__ theta,
                             unsigned short* __restrict__ thetaT) {
  int idx = blockIdx.x * blockDim.x + threadIdx.x;  // 65536 = 128*512
  int n = idx >> 9;
  int k = idx & 511;
  thetaT[idx] = f2bf(theta[k * FOUT + n]);
}

// y[M][128] bf16 = x[M][512] f32 @ thetaT^T, via 16x16x32 bf16 MFMA.
// 128x128 tile, BK=32, 4 waves (2x2, each 64x64).
__global__ __launch_bounds__(256) void gemm_k(const float* __restrict__ x,
                                              const unsigned short* __restrict__ thetaT,
                                              unsigned short* __restrict__ yb, int M) {
  // padded leading dim 40 (80B rows): fragment ds_read_b128 lands 2-way (free)
  __shared__ __align__(16) unsigned short lA[128 * 40];
  __shared__ __align__(16) unsigned short lB[128 * 40];
  const int tid = threadIdx.x;
  const int row0 = blockIdx.x * 128;
  const int wave = tid >> 6, lane = tid & 63;
  const int wm = wave >> 1, wn = wave & 1;
  const int fr = lane & 15, fq = lane >> 4;
  const int arow = tid >> 1, ahalf = tid & 1;

  f32x4 acc[4][4] = {};

  const int grow = row0 + arow;
  const bool aval = (grow < M);
  const float* asrc = x + (size_t)(aval ? grow : 0) * FIN + ahalf * 16;
  const unsigned short* bsrc = thetaT + (size_t)arow * FIN + ahalf * 16;

  for (int k0 = 0; k0 < FIN; k0 += 32) {
    // ---- stage A (f32 -> bf16) ----
    float av[16];
    if (aval) {
      const float4* p = (const float4*)(asrc + k0);
      float4 v0 = p[0], v1 = p[1], v2 = p[2], v3 = p[3];
      av[0] = v0.x; av[1] = v0.y; av[2] = v0.z; av[3] = v0.w;
      av[4] = v1.x; av[5] = v1.y; av[6] = v1.z; av[7] = v1.w;
      av[8] = v2.x; av[9] = v2.y; av[10] = v2.z; av[11] = v2.w;
      av[12] = v3.x; av[13] = v3.y; av[14] = v3.z; av[15] = v3.w;
    } else {
      for (int i = 0; i < 16; i++) av[i] = 0.f;
    }
    unsigned ap[8];
    for (int i = 0; i < 8; i++)
      ap[i] = (unsigned)f2bf(av[2 * i]) | ((unsigned)f2bf(av[2 * i + 1]) << 16);
    uint4* aw = (uint4*)&lA[arow * 40 + ahalf * 16];
    aw[0] = make_uint4(ap[0], ap[1], ap[2], ap[3]);
    aw[1] = make_uint4(ap[4], ap[5], ap[6], ap[7]);

    // ---- stage B (already bf16, straight copy) ----
    const uint4* bp = (const uint4*)(bsrc + k0);
    uint4 b0 = bp[0], b1 = bp[1];
    uint4* bw = (uint4*)&lB[arow * 40 + ahalf * 16];
    bw[0] = b0; bw[1] = b1;

    __syncthreads();

    short8 af[4], bfv[4];
#pragma unroll
    for (int m = 0; m < 4; m++)
      af[m] = *(const short8*)&lA[(wm * 64 + m * 16 + fr) * 40 + fq * 8];
#pragma unroll
    for (int n = 0; n < 4; n++)
      bfv[n] = *(const short8*)&lB[(wn * 64 + n * 16 + fr) * 40 + fq * 8];
#pragma unroll
    for (int m = 0; m < 4; m++)
#pragma unroll
      for (int n = 0; n < 4; n++)
        acc[m][n] = __builtin_amdgcn_mfma_f32_16x16x32_bf16(af[m], bfv[n], acc[m][n], 0, 0, 0);

    __syncthreads();
  }

  // C/D layout: col = lane&15, row = (lane>>4)*4 + reg
#pragma unroll
  for (int m = 0; m < 4; m++) {
    int rbase = row0 + wm * 64 + m * 16 + fq * 4;
#pragma unroll
    for (int j = 0; j < 4; j++) {
      int r = rbase + j;
      if (r < M) {
        unsigned short* dst = yb + (size_t)r * FOUT + wn * 64;
#pragma unroll
        for (int n = 0; n < 4; n++) dst[n * 16 + fr] = f2bf(acc[m][n][j]);
      }
    }
  }
}

__global__ void hist_k(const int* __restrict__ rows, int* __restrict__ counts, int E) {
  int i = blockIdx.x * blockDim.x + threadIdx.x;
  int stride = gridDim.x * blockDim.x;
  for (; i < E; i += stride) atomicAdd(&counts[rows[i]], 1);
}

// ---------------- two-level scan (replaces 229us single-block scan) --------
#define SCHUNK 1024  // counts elements per block

// stage 1: per-block sums
__global__ __launch_bounds__(256) void scan_partial_k(const int* __restrict__ counts,
                                                      int* __restrict__ blockSums, int N) {
  int base = blockIdx.x * SCHUNK;
  int t = threadIdx.x;
  int s = 0;
#pragma unroll
  for (int i = 0; i < SCHUNK / 256; i++) {
    int idx = base + t + i * 256;
    s += (idx < N) ? counts[idx] : 0;
  }
  for (int off = 32; off; off >>= 1) s += __shfl_down(s, off, 64);
  __shared__ int ws[4];
  if ((t & 63) == 0) ws[t >> 6] = s;
  __syncthreads();
  if (t == 0) blockSums[blockIdx.x] = ws[0] + ws[1] + ws[2] + ws[3];
}

// stage 2: single block exclusive scan of blockSums (nb <= 1024)
__global__ __launch_bounds__(1024) void scan_sums_k(int* __restrict__ blockSums, int nb) {
  __shared__ int tmp[1024];
  int t = threadIdx.x;
  tmp[t] = (t < nb) ? blockSums[t] : 0;
  __syncthreads();
  for (int off = 1; off < 1024; off <<= 1) {
    int v = (t >= off) ? tmp[t - off] : 0;
    __syncthreads();
    tmp[t] += v;
    __syncthreads();
  }
  if (t < nb) blockSums[t] = (t == 0) ? 0 : tmp[t - 1];
}

// stage 3: per-block scan + apply block offset; emit offsets[N+1] and cursor
__global__ __launch_bounds__(256) void scan_final_k(const int* __restrict__ counts,
                                                    const int* __restrict__ blockSums,
                                                    int* __restrict__ offsets,
                                                    int* __restrict__ cursor,
                                                    int N, int nb) {
  int b = blockIdx.x;
  int t = threadIdx.x;
  int idx = b * SCHUNK + t * 4;
  int v0 = (idx + 0 < N) ? counts[idx + 0] : 0;
  int v1 = (idx + 1 < N) ? counts[idx + 1] : 0;
  int v2 = (idx + 2 < N) ? counts[idx + 2] : 0;
  int v3 = (idx + 3 < N) ? counts[idx + 3] : 0;
  int local = v0 + v1 + v2 + v3;

  // inclusive wave scan
  int lane = t & 63, w = t >> 6;
  int inc = local;
  for (int off = 1; off < 64; off <<= 1) {
    int u = __shfl_up(inc, off, 64);
    if (lane >= off) inc += u;
  }
  __shared__ int wsum[4];
  if (lane == 63) wsum[w] = inc;
  __syncthreads();
  int woff = 0;
  for (int i = 0; i < 4; i++)
    if (i < w) woff += wsum[i];
  int run = blockSums[b] + woff + inc - local;  // exclusive prefix of this thread

  if (idx + 0 < N) { offsets[idx + 0] = run; cursor[idx + 0] = run; } run += v0;
  if (idx + 1 < N) { offsets[idx + 1] = run; cursor[idx + 1] = run; } run += v1;
  if (idx + 2 < N) { offsets[idx + 2] = run; cursor[idx + 2] = run; } run += v2;
  if (idx + 3 < N) { offsets[idx + 3] = run; cursor[idx + 3] = run; } run += v3;

  if (b == nb - 1 && t == 255) offsets[N] = run;  // grand total
}

__global__ void scatter_k(const int* __restrict__ rows, const int* __restrict__ cols,
                          const float* __restrict__ vals, int* __restrict__ cursor,
                          int* __restrict__ sc, float* __restrict__ sv, int E) {
  int i = blockIdx.x * blockDim.x + threadIdx.x;
  int stride = gridDim.x * blockDim.x;
  for (; i < E; i += stride) {
    int r = rows[i];
    int p = atomicAdd(&cursor[r], 1);
    sc[p] = cols[i];
    sv[p] = vals[i];
  }
}

// one 32-lane group per row: acc 4 feats/lane in regs, fused bias+relu store
__global__ __launch_bounds__(256) void row_k(const int* __restrict__ offsets,
                                             const int* __restrict__ sc,
                                             const float* __restrict__ sv,
                                             const unsigned short* __restrict__ yb,
                                             const float* __restrict__ bias,
                                             float* __restrict__ out, int N) {
  int gid = blockIdx.x * blockDim.x + threadIdx.x;
  int r = gid >> 5, sl = gid & 31;
  if (r >= N) return;
  int s = offsets[r], e = offsets[r + 1];
  float a0 = 0.f, a1 = 0.f, a2 = 0.f, a3 = 0.f;
  for (int i = s; i < e; i++) {
    int c = sc[i];
    float v = sv[i];
    uint2 raw = *(const uint2*)(yb + (size_t)c * FOUT + sl * 4);
    a0 += v * bf2f((unsigned short)(raw.x & 0xffffu));
    a1 += v * bf2f((unsigned short)(raw.x >> 16));
    a2 += v * bf2f((unsigned short)(raw.y & 0xffffu));
    a3 += v * bf2f((unsigned short)(raw.y >> 16));
  }
  const float4 bb = *(const float4*)(bias + sl * 4);
  float4 o;
  o.x = fmaxf(a0 + bb.x, 0.f);
  o.y = fmaxf(a1 + bb.y, 0.f);
  o.z = fmaxf(a2 + bb.z, 0.f);
  o.w = fmaxf(a3 + bb.w, 0.f);
  *(float4*)(out + (size_t)r * FOUT + sl * 4) = o;
}

extern "C" void kernel_launch(void* const* d_in, const int* in_sizes, int n_in,
                              void* d_out, int out_size, void* d_ws, size_t ws_size,
                              hipStream_t stream) {
  const float* x = (const float*)d_in[0];
  const int* rows = (const int*)d_in[1];
  const int* cols = (const int*)d_in[2];
  const float* vals = (const float*)d_in[3];
  const float* theta = (const float*)d_in[4];
  const float* bias = (const float*)d_in[5];
  float* out = (float*)d_out;
  const int M = in_sizes[0] / FIN;  // 100000
  const int E = in_sizes[1];        // 3200000

  char* w = (char*)d_ws;
  auto alloc = [&](size_t bytes) {
    char* p = w;
    w += (bytes + 255) & ~(size_t)255;
    return p;
  };
  unsigned short* yb = (unsigned short*)alloc((size_t)M * FOUT * 2);
  unsigned short* thetaT = (unsigned short*)alloc((size_t)FIN * FOUT * 2);
  int* counts = (int*)alloc((size_t)M * 4);
  int* offsets = (int*)alloc((size_t)(M + 1) * 4);
  int* cursor = (int*)alloc((size_t)M * 4);
  int* sc = (int*)alloc((size_t)E * 4);
  float* sv = (float*)alloc((size_t)E * 4);
  const int nb = (M + SCHUNK - 1) / SCHUNK;  // 98 <= 1024
  int* blockSums = (int*)alloc((size_t)nb * 4);

  hipMemsetAsync(counts, 0, (size_t)M * 4, stream);
  prep_theta_k<<<(FIN * FOUT) / 256, 256, 0, stream>>>(theta, thetaT);
  gemm_k<<<(M + 127) / 128, 256, 0, stream>>>(x, thetaT, yb, M);
  hist_k<<<2048, 256, 0, stream>>>(rows, counts, E);
  scan_partial_k<<<nb, 256, 0, stream>>>(counts, blockSums, M);
  scan_sums_k<<<1, 1024, 0, stream>>>(blockSums, nb);
  scan_final_k<<<nb, 256, 0, stream>>>(counts, blockSums, offsets, cursor, M, nb);
  scatter_k<<<2048, 256, 0, stream>>>(rows, cols, vals, cursor, sc, sv, E);
  row_k<<<(M * 32 + 255) / 256, 256, 0, stream>>>(offsets, sc, sv, yb, bias, out, M);
}